// Round 8
// baseline (94.188 us; speedup 1.0000x reference)
//
#include <hip/hip_runtime.h>

#define K 32
#define DESC 603

typedef _Float16 h8  __attribute__((ext_vector_type(8)));
typedef _Float16 h4v __attribute__((ext_vector_type(4)));
typedef __fp16   fp16x2 __attribute__((ext_vector_type(2)));
typedef float    f32x4 __attribute__((ext_vector_type(4)));

// Wave-private LDS; DS ops of one wave execute in order, so lgkmcnt(0)
// suffices for cross-lane RAW within the wave (no __syncthreads needed).
#define WAVE_LDS_FENCE()  __asm__ volatile("s_waitcnt lgkmcnt(0)" ::: "memory")
#define COMPILER_BARRIER() __asm__ volatile("" ::: "memory")

// per-ATOM LDS slot: 2560 f16 = 5120 B. 4 atoms/block -> 20480 B/block,
// 8 blocks/CU (160 KiB LDS), 16 waves/CU = 32 resident atoms.
//   GT[80][32] rows n' = ch*24 + b*3 + l (rows 0..71 = live GT data)
//   overlay rows 0..7   : sfT[r][k]  (dead after the Bf register read at the
//                         top of phase 2; ch0 writeback rows 0..23 then
//                         overwrites it, after the COMPILER_BARRIER)
//   overlay rows 64..71 : geom arrays (dead after the geom h8 reads at the
//                         top of phase 2; ch2 writeback rows 48..71 comes
//                         after, same body, after the barrier)
//   rows 72..79         : jpack[k] (NEVER written by GT writeback, so the
//                         in-loop jp reads are safe; phase-3 reads of rows
//                         >= 72 feed only unstored D columns)
#define GTB   0
#define SFT   0
#define UHX   2048
#define UHY   2080
#define UHZ   2112
#define MJX   2144
#define MJY   2176
#define MJZ   2208
#define SSK   2240
#define SUK   2272
#define JPK   2304

__device__ __forceinline__ h8 h8splat(float x) {
    _Float16 h = (_Float16)x;
    h8 r = {h,h,h,h,h,h,h,h};
    return r;
}
__device__ __forceinline__ h8 bc(_Float16 h) {
    h8 r = {h,h,h,h,h,h,h,h};
    return r;
}
__device__ __forceinline__ h4v pk4(const f32x4& a) {
    fp16x2 lo = __builtin_amdgcn_cvt_pkrtz(a[0], a[1]);
    fp16x2 hi = __builtin_amdgcn_cvt_pkrtz(a[2], a[3]);
    h4v r;
    r[0] = (_Float16)lo[0]; r[1] = (_Float16)lo[1];
    r[2] = (_Float16)hi[0]; r[3] = (_Float16)hi[1];
    return r;
}

__global__ __launch_bounds__(128, 4)
void desc_kernel(const float* __restrict__ pos, const float* __restrict__ mag,
                 const int* __restrict__ nidx, float* __restrict__ out, int natoms)
{
    __shared__ __align__(16) _Float16 ldsbuf[4][2560];
    const int w = threadIdx.x >> 6;   // wave id (0..1); wave owns atoms w*2, w*2+1
    const int l = threadIdx.x & 63;
    const int col  = l & 15;
    const int quad = l >> 4;
    const int k0   = quad * 8;

    const float CUTOFF  = 4.5f;
    const float SPACING = CUTOFF / 7.0f;
    const float BETA    = 1.0f / (SPACING * SPACING);
    const float INV_U   = 1.0f / 4.84f;
    const float INV_MAG = 1.0f / 2.2f;
    const float PI_F    = 3.14159265358979f;

    int       atomv[2];
    bool      actv[2];
    _Float16* Wv[2];
    h8        Bfv[2];

    #pragma unroll
    for (int u = 0; u < 2; ++u) {
        int a0 = blockIdx.x * 4 + w * 2 + u;
        actv[u] = a0 < natoms;
        if (!actv[u]) a0 = natoms - 1;
        atomv[u] = __builtin_amdgcn_readfirstlane(a0);  // wave-uniform -> SMEM loads
        Wv[u] = &ldsbuf[w * 2 + u][0];
    }

    // ---- phase 1, both atoms: full-wave gather (lanes 0..31 pos, 32..63 mag).
    //      Two independent load chains in flight -> 2x MLP.
    #pragma unroll
    for (int u = 0; u < 2; ++u) {
        const int atom = atomv[u];
        _Float16* W = Wv[u];
        const float pix = pos[3*atom+0], piy = pos[3*atom+1], piz = pos[3*atom+2];
        const float mix = mag[3*atom+0], miy = mag[3*atom+1], miz = mag[3*atom+2];

        const int k = l & 31;
        const int n = nidx[atom*K + k];
        const float* src = (l < K) ? (pos + 3*n) : (mag + 3*n);
        const float v0 = src[0], v1 = src[1], v2 = src[2];

        if (l < K) {
            const float vx = v0 - pix, vy = v1 - piy, vz = v2 - piz;
            const float d  = sqrtf(vx*vx + vy*vy + vz*vz + 1e-8f);
            const float rd = 1.0f / d;
            const _Float16 hx = (_Float16)(vx*rd), hy = (_Float16)(vy*rd), hz = (_Float16)(vz*rd);
            W[UHX+k] = hx; W[UHY+k] = hy; W[UHZ+k] = hz;
            h4v jp = {hx, hy, hz, (_Float16)0.0f};
            *(h4v*)&W[JPK + k*8] = jp;
            float cut = 0.0f;
            if (d < CUTOFF) cut = 0.5f * (__cosf(PI_F * d / CUTOFF) + 1.0f);
            #pragma unroll
            for (int r = 0; r < 8; ++r) {
                const float diff = d - (float)r * SPACING;
                W[SFT + r*32 + k] = (_Float16)(__expf(-BETA * diff * diff) * cut);
            }
        } else {
            const float mx = v0*INV_MAG, my = v1*INV_MAG, mz = v2*INV_MAG;
            const float ss = (mix*v0 + miy*v1 + miz*v2) * INV_U;
            const float su = (v0*v0 + v1*v1 + v2*v2) * INV_U;
            const _Float16 hmx = (_Float16)mx, hmy = (_Float16)my, hmz = (_Float16)mz;
            W[MJX+k] = hmx; W[MJY+k] = hmy; W[MJZ+k] = hmz;
            W[SSK+k] = (_Float16)ss; W[SUK+k] = (_Float16)su;
            h4v jp = {hmx, hmy, hmz, (_Float16)ss};
            *(h4v*)&W[JPK + k*8 + 4] = jp;
        }
        if (l == 32 && actv[u]) {
            const float un = (mix*mix + miy*miy + miz*miz) * INV_U;
            out[atom*DESC+0] = un; out[atom*DESC+1] = un*un; out[atom*DESC+2] = un*un*un;
        }
    }
    WAVE_LDS_FENCE();

    // ---- rho + phase 2, both atoms ----
    #pragma unroll
    for (int u = 0; u < 2; ++u) {
        const int atom = atomv[u];
        const bool act = actv[u];
        _Float16* W = Wv[u];

        // per-atom hoisted reads; sfT (rows 0..7) and geom (rows 64..71)
        // die after these and are clobbered by GT writebacks below
        const h8 Bf   = *(const h8*)&W[SFT + (col&7)*32 + k0];
        const h8 uhx8 = *(const h8*)&W[UHX + k0];
        const h8 uhy8 = *(const h8*)&W[UHY + k0];
        const h8 uhz8 = *(const h8*)&W[UHZ + k0];
        const h8 mjx8 = *(const h8*)&W[MJX + k0];
        const h8 mjy8 = *(const h8*)&W[MJY + k0];
        const h8 mjz8 = *(const h8*)&W[MJZ + k0];
        const h8 ssk8 = *(const h8*)&W[SSK + k0];
        const h8 suk8 = *(const h8*)&W[SUK + k0];
        Bfv[u] = Bf;
        COMPILER_BARRIER();   // GT writebacks must not move above these reads

        // rho MFMA: rows {1, u_k, s_k} @ F
        {
            h8 Ar = h8splat(0.0f);
            if      (col == 0) Ar = h8splat(1.0f);
            else if (col == 1) Ar = suk8;
            else if (col == 2) Ar = ssk8;
            f32x4 d = __builtin_amdgcn_mfma_f32_16x16x32_f16(Ar, Bf, (f32x4){0,0,0,0}, 0,0,0);
            if (act && quad == 0 && col < 8) {
                out[atom*DESC + 3   + col] = d[0];   // rho_r
                out[atom*DESC + 203 + col] = d[1];   // rho_uj
                out[atom*DESC + 211 + col] = d[2];   // rho_s
            }
        }

        // G_q(32x8) = C_q(32x32) @ F(32x8), two j-tiles
        #pragma unroll
        for (int t = 0; t < 2; ++t) {
            const int j  = t*16 + col;
            const h8 jp  = *(const h8*)&W[JPK + j*8];   // rows 72..79: never clobbered
            h8 c = uhx8*bc(jp[0]) + uhy8*bc(jp[1]) + uhz8*bc(jp[2]);
            c = __builtin_elementwise_min(h8splat(1.0f),
                __builtin_elementwise_max(h8splat(-1.0f), c));
            const h8 P1 = c;
            const h8 P2 = c * c * h8splat(1.5f) - h8splat(0.5f);
            h8 wv  = mjx8*bc(jp[4]) + mjy8*bc(jp[5]) + mjz8*bc(jp[6]);
            h8 wiv = ssk8*bc(jp[7]);
            h8 mk;
            #pragma unroll
            for (int e = 0; e < 8; ++e)
                mk[e] = (_Float16)((k0 + e > j) ? 1.0f : 0.0f);

            const int tcol = t*16 + quad*4;
            const f32x4 z4 = {0,0,0,0};
            #pragma unroll
            for (int ch = 0; ch < 3; ++ch) {
                const h8 Bv = (ch == 0) ? mk : (ch == 1) ? wv*mk : wiv*mk;
                f32x4 a0 = __builtin_amdgcn_mfma_f32_16x16x32_f16(Bv,    Bf, z4, 0,0,0);
                f32x4 a1 = __builtin_amdgcn_mfma_f32_16x16x32_f16(Bv*P1, Bf, z4, 0,0,0);
                f32x4 a2 = __builtin_amdgcn_mfma_f32_16x16x32_f16(Bv*P2, Bf, z4, 0,0,0);
                if (col < 8) {
                    const int row = ch*24 + col*3;     // n' = ch*24 + b*3 + l
                    *(h4v*)&W[GTB + (row+0)*32 + tcol] = pk4(a0);
                    *(h4v*)&W[GTB + (row+1)*32 + tcol] = pk4(a1);
                    *(h4v*)&W[GTB + (row+2)*32 + tcol] = pk4(a2);
                }
            }
        }
    }
    WAVE_LDS_FENCE();

    // ---- phase 3, both atoms: A_out(8a x 72) = F^T(8x32) @ G(32x72) ----
    #pragma unroll
    for (int u = 0; u < 2; ++u) {
        const int atom = atomv[u];
        const bool act = actv[u];
        _Float16* W = Wv[u];
        const h8 Bf = Bfv[u];
        #pragma unroll
        for (int nt = 0; nt < 5; ++nt) {
            const int n = nt*16 + col;
            const h8 Bg = *(const h8*)&W[GTB + n*32 + k0];
            const f32x4 d = __builtin_amdgcn_mfma_f32_16x16x32_f16(Bf, Bg, (f32x4){0,0,0,0}, 0,0,0);
            if (act && quad < 2 && n < 72) {
                const int ch  = n / 24;
                const int off = n - ch*24;             // b*3 + l
                const int cb  = (ch == 0) ? 11 : ((ch == 1) ? 219 : 411);
                const int base = atom*DESC + cb + off + quad*96;
                #pragma unroll
                for (int reg = 0; reg < 4; ++reg)
                    out[base + reg*24] = d[reg];
            }
        }
    }
}

extern "C" void kernel_launch(void* const* d_in, const int* in_sizes, int n_in,
                              void* d_out, int out_size, void* d_ws, size_t ws_size,
                              hipStream_t stream) {
    const float* pos  = (const float*)d_in[0];
    const float* mag  = (const float*)d_in[1];
    const int*   nidx = (const int*)d_in[2];
    float* out = (float*)d_out;
    const int n_atoms = in_sizes[2] / K;            // 20000
    const int blocks = (n_atoms + 3) / 4;           // 4 atoms per 128-thread block
    desc_kernel<<<blocks, 128, 0, stream>>>(pos, mag, nidx, out, n_atoms);
}